// Round 5
// baseline (194.712 us; speedup 1.0000x reference)
//
#include <hip/hip_runtime.h>

// UpsampleRFFT (zero-insert 2x + ideal half-band low-pass, circular), closed form:
//   g[j] = sign*cot(pi*(2j+1)/256)/128, sign=+ if j even
//   out[2r][2i]   = x[r][i] (exact fp32)      out[2r][2i+1] = T[r][i],  T = X*G
//   out[2p+1][c]  = sum_m g[(p-m)&127] * E[m][c],  E = even rows
// 2 blocks per image (output-column halves) so LDS halves -> 4 blocks/CU.
// Phase A: T via MFMA (row-resident X, transposed GEMM), writes even rows to
// global and E^T (bf16) into LDS. Phase B: odd rows = G*E from LDS E^T.
// Tap frags (8/lane, A/B-role-shared, R2-verified lane/k convention) in d_ws.

typedef __bf16 bf16x8 __attribute__((ext_vector_type(8)));
typedef float  f32x4  __attribute__((ext_vector_type(4)));

#define W2 136        // Et pitch in bf16: 272B rows, 16B-aligned
#define PI_F 3.14159265358979323846f

__device__ __forceinline__ unsigned short f2bf(float x) {
    unsigned int b = __float_as_uint(x);
    return (unsigned short)((b + 0x7FFFu + ((b >> 16) & 1u)) >> 16);  // RNE
}

__device__ __forceinline__ float gfun(int j) {           // g[j & 127]
    int d = 2 * (j & 127) + 1;
    float th = PI_F * (float)d * (1.0f / 256.0f);
    float s  = ((d & 3) == 1) ? 1.0f : -1.0f;
    return s * cosf(th) / (128.0f * sinf(th));
}

// ---- init: per-lane tap fragment table (8 frags x 64 lanes x 8 bf16 = 8KB) ----
__global__ __launch_bounds__(512)
void init_ghtab(unsigned short* __restrict__ ghtab)
{
    const int t    = threadIdx.x;         // t = dd*64 + lane
    const int lane = t & 63;
    const int l15  = lane & 15;
    const int l4   = lane >> 4;
    const int dd   = t >> 6;
    const int base = l15 - 8 * l4 + 16 * dd;
    unsigned short u[8];
    #pragma unroll
    for (int e = 0; e < 8; ++e) u[e] = f2bf(gfun(base - e));
    *(ushort4*)&ghtab[t * 8]     = make_ushort4(u[0], u[1], u[2], u[3]);
    *(ushort4*)&ghtab[t * 8 + 4] = make_ushort4(u[4], u[5], u[6], u[7]);
}

// ---- fused kernel: 2 blocks/image (c-halves), 512 threads (8 waves) ----
__global__ __launch_bounds__(512, 8)
void upsample_fused(const float* __restrict__ xin, float* __restrict__ out,
                    const unsigned short* __restrict__ ghtab)
{
    __shared__ __align__(16) __bf16 Et[128 * W2];  // Et[c_local][m] = E[m][128*cb+c]
    __shared__ float gtab[128];                    // fallback only

    const int tid  = threadIdx.x;
    const int lane = tid & 63;
    const int w    = tid >> 6;        // 0..7: r-tile (A) and p-tile (B)
    const int l15  = lane & 15;
    const int l4   = lane >> 4;

    const long long img = blockIdx.x >> 1;
    const int cb        = blockIdx.x & 1;          // column half
    const float* __restrict__ xim = xin + img * (128LL * 128LL);
    float*       __restrict__ oim = out + img * (256LL * 256LL);

    const int r = 16 * w + l15;
    const float* __restrict__ xrow = xim + r * 128;

    // issue full-row x loads first (K=128 needed for the W-conv)
    float4 xlo[4], xhi[4];
    #pragma unroll
    for (int t = 0; t < 4; ++t) {
        xlo[t] = *(const float4*)&xrow[32 * t + 8 * l4];
        xhi[t] = *(const float4*)&xrow[32 * t + 8 * l4 + 4];
    }

    // tap fragments: 8 coalesced 16B loads from precomputed table
    bf16x8 gh[8];
    if (ghtab) {
        #pragma unroll
        for (int dd = 0; dd < 8; ++dd)
            gh[dd] = *(const bf16x8*)&ghtab[(dd * 64 + lane) * 8];
    } else {
        if (tid < 128) gtab[tid] = gfun(tid);
        __syncthreads();
        #pragma unroll
        for (int dd = 0; dd < 8; ++dd) {
            union { bf16x8 v; unsigned short u[8]; } H;
            int base = l15 - 8 * l4 + 16 * dd;
            #pragma unroll
            for (int e = 0; e < 8; ++e) H.u[e] = f2bf(gtab[(base - e) & 127]);
            gh[dd] = H.v;
        }
    }

    // X fragments (native bf16 cvt) ; even cols of E^T for this c-half
    union { bf16x8 v; __bf16 h[8]; } xa[4];
    #pragma unroll
    for (int t = 0; t < 4; ++t) {
        xa[t].h[0] = (__bf16)xlo[t].x; xa[t].h[1] = (__bf16)xlo[t].y;
        xa[t].h[2] = (__bf16)xlo[t].z; xa[t].h[3] = (__bf16)xlo[t].w;
        xa[t].h[4] = (__bf16)xhi[t].x; xa[t].h[5] = (__bf16)xhi[t].y;
        xa[t].h[6] = (__bf16)xhi[t].z; xa[t].h[7] = (__bf16)xhi[t].w;
    }
    #pragma unroll
    for (int tt = 0; tt < 2; ++tt) {               // t = 2*cb + tt covers this half
        const int t = 2 * cb + tt;
        #pragma unroll
        for (int e = 0; e < 8; ++e)
            Et[(64 * tt + 16 * l4 + 2 * e) * W2 + r] = xa[t].h[e];
    }

    // ---- phase A: T = X*G (transposed); even output rows + odd cols of E^T ----
    float* __restrict__ orow = oim + (2 * r) * 256 + 128 * cb;
    #pragma unroll
    for (int mt = 0; mt < 4; ++mt) {
        f32x4 acc = {0.f, 0.f, 0.f, 0.f};
        #pragma unroll
        for (int t = 0; t < 4; ++t)
            acc = __builtin_amdgcn_mfma_f32_16x16x32_bf16(gh[(4 * cb + mt - 2 * t) & 7],
                                                          xa[t].v, acc, 0, 0, 0);
        const int i0l = 16 * mt + 4 * l4;          // local i in [0,64)
        float4 xc = *(const float4*)&xrow[64 * cb + i0l];   // L1 hit, exact fp32
        float4 o0 = make_float4(xc.x, acc[0], xc.y, acc[1]);
        float4 o1 = make_float4(xc.z, acc[2], xc.w, acc[3]);
        *(float4*)&orow[2 * i0l]     = o0;
        *(float4*)&orow[2 * i0l + 4] = o1;
        #pragma unroll
        for (int q = 0; q < 4; ++q)
            Et[(2 * (i0l + q) + 1) * W2 + r] = (__bf16)acc[q];
    }
    __syncthreads();

    // ---- phase B: odd[p][c] = sum_m g[(p-m)&127] * E[m][c] ----
    {
        float* __restrict__ prow = oim + (2 * (16 * w + l15) + 1) * 256 + 128 * cb;
        #pragma unroll
        for (int mc = 0; mc < 8; ++mc) {
            f32x4 acc = {0.f, 0.f, 0.f, 0.f};
            #pragma unroll
            for (int t = 0; t < 4; ++t) {
                bf16x8 ef = *(const bf16x8*)&Et[(16 * mc + l15) * W2 + 32 * t + 8 * l4];
                acc = __builtin_amdgcn_mfma_f32_16x16x32_bf16(ef, gh[(w - 2 * t) & 7],
                                                              acc, 0, 0, 0);
            }
            float4 o = make_float4(acc[0], acc[1], acc[2], acc[3]);
            *(float4*)&prow[16 * mc + 4 * l4] = o;   // p=16w+l15, c=16mc+4l4+q
        }
    }
}

extern "C" void kernel_launch(void* const* d_in, const int* in_sizes, int n_in,
                              void* d_out, int out_size, void* d_ws, size_t ws_size,
                              hipStream_t stream)
{
    (void)n_in; (void)out_size;
    const float* x = (const float*)d_in[0];
    float* out = (float*)d_out;
    int nimg = in_sizes[0] / (128 * 128);   // 1024 images

    unsigned short* ghtab = nullptr;
    if (ws_size >= 8192) {
        ghtab = (unsigned short*)d_ws;
        hipLaunchKernelGGL(init_ghtab, dim3(1), dim3(512), 0, stream, ghtab);
    }
    hipLaunchKernelGGL(upsample_fused, dim3(nimg * 2), dim3(512), 0, stream, x, out, ghtab);
}